// Round 15
// baseline (932.596 us; speedup 1.0000x reference)
//
#include <hip/hip_runtime.h>
#include <hip/hip_bf16.h>

typedef float f32x4 __attribute__((ext_vector_type(4)));
typedef int   i32x4 __attribute__((ext_vector_type(4)));
typedef short s16x8 __attribute__((ext_vector_type(8)));
typedef unsigned short u16;

#define BT 16        // rows per tile
#define NWG 128      // 16 groups x 8 h-slices; each WG: 4 tiles (2 pairs)
#define NTH 512      // 8 waves
#define PREPTH 256
#define H 128
#define VW 256
#define NI 64
#define NSTEPS 64

// ws BYTE layout:
#define OFF_FRAG16 0        // u16 frags: W1 (32768 u16) + W2 (65536 u16) = 196608 B
#define OFF_WMQ    196608   // i8 frags [slice8][l21][kk4][lane64][16] = 688128 B
#define OFF_BMF    884736   // f32 [slice8][l21][hh16] = 10752 B
#define OFF_SCF    895488   // f32[128]
#define OFF_SINV   896000   // f32[128]
#define OFF_YBUF   896512   // u32 [64 tile][2 parity][2048] = 1 MB
#define YBUF_BYTES 1048576

#define MFMA_BF16(a,b,c) __builtin_amdgcn_mfma_f32_16x16x32_bf16(a,b,c,0,0,0)
#define MFMA_I8(a,b,c)   __builtin_amdgcn_mfma_i32_16x16x64_i8(a,b,c,0,0,0)

__device__ __forceinline__ u16 bf16u(float f) {
  union { float f; unsigned u; } x; x.f = f;
  return (u16)((x.u + 0x7fffu + ((x.u >> 16) & 1u)) >> 16);  // RNE
}
__device__ __forceinline__ float b2f(u16 u) {
  union { unsigned u; float f; } x; x.u = ((unsigned)u) << 16;
  return x.f;
}

// -------- prep 1: per-h max of |Wm| -> scales --------
__global__ void prep_scales(const float* __restrict__ Wm, char* __restrict__ ws) {
  __shared__ float red[4];
  const int tid = threadIdx.x;
  const int h = blockIdx.x;
  float m = 0.f;
  for (int i = tid; i < 21 * VW; i += PREPTH) m = fmaxf(m, fabsf(Wm[h * 21 * VW + i]));
  for (int off = 32; off > 0; off >>= 1) m = fmaxf(m, __shfl_down(m, off));
  if ((tid & 63) == 0) red[tid >> 6] = m;
  __syncthreads();
  if (tid == 0) {
    m = fmaxf(fmaxf(red[0], red[1]), fmaxf(red[2], red[3]));
    m = fmaxf(m, 1e-20f);
    ((float*)(ws + OFF_SCF))[h]  = m / 16129.f;   // max/(127*127)
    ((float*)(ws + OFF_SINV))[h] = 127.f / m;
  }
}

// -------- prep 2: pack W1/W2 bf16 frags, Wm i8 frags, bm slices --------
__global__ void prep_pack(const float* __restrict__ Wvf1, const float* __restrict__ Wvf2,
                          const float* __restrict__ Wm, const float* __restrict__ bmv,
                          char* __restrict__ ws) {
  int idx = blockIdx.x * blockDim.x + threadIdx.x;
  if (idx < 98304) {
    u16* w16 = (u16*)(ws + OFF_FRAG16);
    float val;
    if (idx < 32768) {
      int e = idx;
      int j = e & 7, ln = (e >> 3) & 63, nt = (e >> 9) & 15, kk = e >> 13;
      val = Wvf1[(nt * 16 + (ln & 15)) * H + kk * 32 + (ln >> 4) * 8 + j];
    } else {
      int e = idx - 32768;
      int j = e & 7, ln = (e >> 3) & 63, nt = (e >> 9) & 15, kk = e >> 13;
      val = Wvf2[(nt * 16 + (ln & 15)) * VW + kk * 32 + (ln >> 4) * 8 + j];
    }
    w16[idx] = bf16u(val);
  } else if (idx < 98304 + 688128) {
    int b = idx - 98304;
    int j = b & 15, lane = (b >> 4) & 63, kk = (b >> 10) & 3, rem = b >> 12;
    int l = rem % 21, nt = rem / 21;
    int h = nt * 16 + (lane & 15);
    int w = kk * 64 + (lane >> 4) * 16 + j;
    float sinv = ((const float*)(ws + OFF_SINV))[h];
    float val = Wm[(size_t)(h * 21 + l) * VW + w];
    int q = (int)lrintf(val * sinv);
    q = min(127, max(-127, q));
    ((signed char*)(ws + OFF_WMQ))[b] = (signed char)q;
  } else if (idx < 98304 + 688128 + 2688) {
    int b = idx - (98304 + 688128);
    int hh = b & 15, rem = b >> 4;
    int l = rem % 21, nt = rem / 21;
    ((float*)(ws + OFF_BMF))[b] = bmv[(nt * 16 + hh) * 21 + l];
  }
}

// -------- main persistent kernel: R8 4-phase schedule, 2 pairs (4 tiles)/WG --------
__global__ __launch_bounds__(NTH, 1) void rde_main(
    const float* __restrict__ logsig, const float* __restrict__ x0,
    const float* __restrict__ W1, const float* __restrict__ b1,
    const float* __restrict__ bvf1, const float* __restrict__ bvf2,
    const float* __restrict__ W2, const float* __restrict__ b2,
    char* __restrict__ ws, float* __restrict__ out) {
  __shared__ __align__(16) signed char WmL[86016];     // i8 Wm slice (shared by all tiles)
  __shared__ __align__(16) u16   YB [4][BT][H + 8];    // per-tile bf16 y
  __shared__ __align__(16) u16   V1R[2][BT][VW + 8];   // per-pair, time-shared A/B
  __shared__ __align__(16) signed char V2QH[2][4096];  // per-pair
  __shared__ __align__(16) float LSF[4][2][21][BT];    // [tile][interval parity][l][r]
  __shared__ __align__(16) float part[2][8][BT][17];   // per-pair (aliased as LG at end)
  __shared__ __align__(16) float bmL[336];
  __shared__ float scL[16];

  const int tid = threadIdx.x;
  const int lane = tid & 63;
  const int wv = tid >> 6;     // 0..7
  const int c = lane & 15;
  const int kg = lane >> 4;
  const int bid = blockIdx.x;
  const int Gp = bid & 15;     // group 0..15; slices share bid&7 -> same XCD (heuristic)
  const int t = bid >> 4;      // h-slice 0..7
  const int b0 = Gp * 64;
  unsigned* __restrict__ ybuf = (unsigned*)(ws + OFF_YBUF);
  const s16x8* __restrict__ fr16 = (const s16x8*)(ws + OFF_FRAG16);
  const f32x4 zf = {0.f, 0.f, 0.f, 0.f};
  const i32x4 zi = {0, 0, 0, 0};

  // persistent register weights: wave handles n-tiles {2wv, 2wv+1}
  s16x8 w1r[2][4], w2r[2][8];
#pragma unroll
  for (int n = 0; n < 2; ++n) {
#pragma unroll
    for (int kk = 0; kk < 4; ++kk) w1r[n][kk] = fr16[(kk * 16 + wv * 2 + n) * 64 + lane];
#pragma unroll
    for (int kk = 0; kk < 8; ++kk) w2r[n][kk] = fr16[4096 + (kk * 16 + wv * 2 + n) * 64 + lane];
  }
  float bv1[2], bv2[2];
#pragma unroll
  for (int n = 0; n < 2; ++n) {
    bv1[n] = bvf1[wv * 32 + n * 16 + c];
    bv2[n] = bvf2[wv * 32 + n * 16 + c];
  }

  {  // Wm slice -> LDS (once)
    const i32x4* wsrc = (const i32x4*)(ws + OFF_WMQ + t * 86016);
    i32x4* wdst = (i32x4*)WmL;
    for (int e = tid; e < 5376; e += NTH) wdst[e] = wsrc[e];
  }
  if (tid < 16) scL[tid] = ((const float*)(ws + OFF_SCF))[t * 16 + tid];
  if (tid < 336) bmL[tid] = ((const float*)(ws + OFF_BMF))[t * 336 + tid];

  // y0 = x0 @ W1^T + b1 for 4 tiles (full YB + own state elements)
  for (int e = tid; e < 4 * BT * H; e += NTH) {
    int tt = e >> 11, r = (e >> 7) & 15, h = e & 127;
    float a = b1[h];
#pragma unroll
    for (int d = 0; d < 6; ++d) a += x0[(b0 + tt * 16 + r) * 6 + d] * W1[h * 6 + d];
    YB[tt][r][h] = bf16u(a);
  }
  float y0s = 0.f, y1s = 0.f, y2s = 0.f, y3s = 0.f;
  float yp0s = 0.f, yp1s = 0.f, yp2s = 0.f, yp3s = 0.f;
  if (tid < 256) {
    int r = tid >> 4, hh = tid & 15, h = t * 16 + hh;
    float a0 = b1[h], a1 = b1[h], a2 = b1[h], a3 = b1[h];
#pragma unroll
    for (int d = 0; d < 6; ++d) {
      float w = W1[h * 6 + d];
      a0 += x0[(b0 + r) * 6 + d] * w;
      a1 += x0[(b0 + 16 + r) * 6 + d] * w;
      a2 += x0[(b0 + 32 + r) * 6 + d] * w;
      a3 += x0[(b0 + 48 + r) * 6 + d] * w;
    }
    y0s = a0; y1s = a1; y2s = a2; y3s = a3;
  }

  // ---- stage helpers (R8 verbatim, + pair index p) ----
  auto STAGE = [&](int T, int iv) {
    if (tid < BT * 21) {
      int r = tid / 21, l = tid - r * 21;
      LSF[T][iv & 1][l][r] = logsig[((size_t)(b0 + T * 16 + r) * NI + iv) * 22 + 1 + l];
    }
  };
  auto S1 = [&](int T, int p) {  // YB[T] -> V1R[p]
    s16x8 ay0 = *(const s16x8*)&YB[T][c][0 * 32 + kg * 8];
    s16x8 ay1 = *(const s16x8*)&YB[T][c][1 * 32 + kg * 8];
    s16x8 ay2 = *(const s16x8*)&YB[T][c][2 * 32 + kg * 8];
    s16x8 ay3 = *(const s16x8*)&YB[T][c][3 * 32 + kg * 8];
    f32x4 pA = MFMA_BF16(ay0, w1r[0][0], zf), pB = MFMA_BF16(ay0, w1r[1][0], zf);
    pA = MFMA_BF16(ay1, w1r[0][1], pA);  pB = MFMA_BF16(ay1, w1r[1][1], pB);
    pA = MFMA_BF16(ay2, w1r[0][2], pA);  pB = MFMA_BF16(ay2, w1r[1][2], pB);
    pA = MFMA_BF16(ay3, w1r[0][3], pA);  pB = MFMA_BF16(ay3, w1r[1][3], pB);
#pragma unroll
    for (int q = 0; q < 4; ++q) {
      V1R[p][kg * 4 + q][wv * 32 + c]      = bf16u(fmaxf(pA[q] + bv1[0], 0.f));
      V1R[p][kg * 4 + q][wv * 32 + 16 + c] = bf16u(fmaxf(pB[q] + bv1[1], 0.f));
    }
  };
  auto S2 = [&](int p) {  // V1R[p] -> V2QH[p]
    s16x8 av0 = *(const s16x8*)&V1R[p][c][0 * 32 + kg * 8];
    s16x8 av1 = *(const s16x8*)&V1R[p][c][1 * 32 + kg * 8];
    s16x8 av2 = *(const s16x8*)&V1R[p][c][2 * 32 + kg * 8];
    s16x8 av3 = *(const s16x8*)&V1R[p][c][3 * 32 + kg * 8];
    s16x8 av4 = *(const s16x8*)&V1R[p][c][4 * 32 + kg * 8];
    s16x8 av5 = *(const s16x8*)&V1R[p][c][5 * 32 + kg * 8];
    s16x8 av6 = *(const s16x8*)&V1R[p][c][6 * 32 + kg * 8];
    s16x8 av7 = *(const s16x8*)&V1R[p][c][7 * 32 + kg * 8];
    f32x4 pA = MFMA_BF16(av0, w2r[0][0], zf), pB = MFMA_BF16(av0, w2r[1][0], zf);
    pA = MFMA_BF16(av1, w2r[0][1], pA);  pB = MFMA_BF16(av1, w2r[1][1], pB);
    pA = MFMA_BF16(av2, w2r[0][2], pA);  pB = MFMA_BF16(av2, w2r[1][2], pB);
    pA = MFMA_BF16(av3, w2r[0][3], pA);  pB = MFMA_BF16(av3, w2r[1][3], pB);
    pA = MFMA_BF16(av4, w2r[0][4], pA);  pB = MFMA_BF16(av4, w2r[1][4], pB);
    pA = MFMA_BF16(av5, w2r[0][5], pA);  pB = MFMA_BF16(av5, w2r[1][5], pB);
    pA = MFMA_BF16(av6, w2r[0][6], pA);  pB = MFMA_BF16(av6, w2r[1][6], pB);
    pA = MFMA_BF16(av7, w2r[0][7], pA);  pB = MFMA_BF16(av7, w2r[1][7], pB);
#pragma unroll
    for (int n = 0; n < 2; ++n) {
      f32x4 pp = n ? pB : pA;
#pragma unroll
      for (int q = 0; q < 4; ++q) {
        float x = pp[q] + bv2[n];
        float e2 = __expf(2.f * x);
        float t127 = fmaf(-254.f, __builtin_amdgcn_rcpf(e2 + 1.f), 127.f);  // 127*tanh
        int bo = ((wv >> 1) * 64 + ((wv & 1) * 2 + n) * 16 + kg * 4 + q) * 16 + c;
        V2QH[p][bo] = (signed char)(int)rintf(t127);
      }
    }
  };
  auto S3 = [&](int T, int p, int lsb_) {  // V2QH[p] x WmL -> part[p]
    i32x4 aih0 = *(const i32x4*)&V2QH[p][(0 * 64 + lane) * 16];
    i32x4 aih1 = *(const i32x4*)&V2QH[p][(1 * 64 + lane) * 16];
    i32x4 aih2 = *(const i32x4*)&V2QH[p][(2 * 64 + lane) * 16];
    i32x4 aih3 = *(const i32x4*)&V2QH[p][(3 * 64 + lane) * 16];
    const int nl = (wv < 5) ? 3 : 2;
    const int lb = (wv < 5) ? 3 * wv : 15 + 2 * (wv - 5);
    f32x4 acc = zf;
    for (int li = 0; li < nl; ++li) {
      int l = lb + li;
      const i32x4* bp = (const i32x4*)WmL + l * 256 + lane;
      i32x4 bq0 = bp[0], bq1 = bp[64], bq2 = bp[128], bq3 = bp[192];
      i32x4 PH = MFMA_I8(aih0, bq0, zi);
      PH = MFMA_I8(aih1, bq1, PH);
      PH = MFMA_I8(aih2, bq2, PH);
      PH = MFMA_I8(aih3, bq3, PH);
      f32x4 ls4 = *(const f32x4*)&LSF[T][lsb_][l][kg * 4];
#pragma unroll
      for (int q = 0; q < 4; ++q) acc[q] += ls4[q] * (float)PH[q];
    }
#pragma unroll
    for (int q = 0; q < 4; ++q) part[p][wv][kg * 4 + q][c] = acc[q];
  };
  auto S4 = [&](int T, int p, int j, int lsb_, float& y, float& yp) {  // Heun + store
    if (tid < 256) {
      int r = tid >> 4, hh = tid & 15;
      float s = ((part[p][0][r][hh] + part[p][1][r][hh]) +
                 (part[p][2][r][hh] + part[p][3][r][hh])) +
                ((part[p][4][r][hh] + part[p][5][r][hh]) +
                 (part[p][6][r][hh] + part[p][7][r][hh]));
      float bmd = 0.f;
#pragma unroll
      for (int l = 0; l < 21; ++l) bmd += LSF[T][lsb_][l][r] * bmL[l * 16 + hh];
      float raw = scL[hh] * s + bmd;
      float yn;
      if (!(j & 1)) { yp = y + 0.5f * raw; yn = y + raw; }
      else          { y = yp + 0.5f * raw; yn = y; }
      unsigned v = ((unsigned)(j + 1) << 16) | (unsigned)bf16u(yn);
      __hip_atomic_store(&ybuf[((Gp * 4 + T) * 2 + (j & 1)) * 2048 + r * 128 + t * 16 + hh],
                         v, __ATOMIC_RELAXED, __HIP_MEMORY_SCOPE_AGENT);
    }
  };
  auto S5_2 = [&](int Ta, int Tb, int j) {  // combined poll of two tiles, rebuild both YB
    const unsigned tg = (unsigned)(j + 1);
    const unsigned* pa = ybuf + ((Gp * 4 + Ta) * 2 + (j & 1)) * 2048;
    const unsigned* pb = ybuf + ((Gp * 4 + Tb) * 2 + (j & 1)) * 2048;
    unsigned a0, a1, a2, a3, e0, e1, e2, e3;
#pragma unroll 1
    for (int sp = 0; sp < 60000; ++sp) {
      a0 = __hip_atomic_load(&pa[tid],        __ATOMIC_RELAXED, __HIP_MEMORY_SCOPE_AGENT);
      a1 = __hip_atomic_load(&pa[tid + 512],  __ATOMIC_RELAXED, __HIP_MEMORY_SCOPE_AGENT);
      a2 = __hip_atomic_load(&pa[tid + 1024], __ATOMIC_RELAXED, __HIP_MEMORY_SCOPE_AGENT);
      a3 = __hip_atomic_load(&pa[tid + 1536], __ATOMIC_RELAXED, __HIP_MEMORY_SCOPE_AGENT);
      e0 = __hip_atomic_load(&pb[tid],        __ATOMIC_RELAXED, __HIP_MEMORY_SCOPE_AGENT);
      e1 = __hip_atomic_load(&pb[tid + 512],  __ATOMIC_RELAXED, __HIP_MEMORY_SCOPE_AGENT);
      e2 = __hip_atomic_load(&pb[tid + 1024], __ATOMIC_RELAXED, __HIP_MEMORY_SCOPE_AGENT);
      e3 = __hip_atomic_load(&pb[tid + 1536], __ATOMIC_RELAXED, __HIP_MEMORY_SCOPE_AGENT);
      unsigned mn = min(min(a0 >> 16, a1 >> 16), min(a2 >> 16, a3 >> 16));
      mn = min(mn, min(min(e0 >> 16, e1 >> 16), min(e2 >> 16, e3 >> 16)));
      if (mn == tg) break;
    }
    YB[Ta][tid >> 7][tid & 127] = (u16)(a0 & 0xffffu);
    YB[Ta][(tid + 512) >> 7][(tid + 512) & 127] = (u16)(a1 & 0xffffu);
    YB[Ta][(tid + 1024) >> 7][(tid + 1024) & 127] = (u16)(a2 & 0xffffu);
    YB[Ta][(tid + 1536) >> 7][(tid + 1536) & 127] = (u16)(a3 & 0xffffu);
    YB[Tb][tid >> 7][tid & 127] = (u16)(e0 & 0xffffu);
    YB[Tb][(tid + 512) >> 7][(tid + 512) & 127] = (u16)(e1 & 0xffffu);
    YB[Tb][(tid + 1024) >> 7][(tid + 1024) & 127] = (u16)(e2 & 0xffffu);
    YB[Tb][(tid + 1536) >> 7][(tid + 1536) & 127] = (u16)(e3 & 0xffffu);
  };

  __syncthreads();

  // ---- prologue: B-tiles (T1, T3) run S1,S2 of sub-step 0
  STAGE(1, 0);
  STAGE(3, 0);
  __syncthreads();
  S1(1, 0);
  S1(3, 1);
  __syncthreads();
  S2(0);
  S2(1);
  __syncthreads();

#pragma unroll 1
  for (int j = 0; j < 2 * NSTEPS; ++j) {
    const int step_ = j >> 1, sub_ = j & 1;
    const int lsb_ = (sub_ ? step_ : (step_ > 0 ? step_ - 1 : 0)) & 1;
    // p0: S1(A) || S3(B), both pairs
    if (!sub_) { STAGE(0, step_); STAGE(2, step_); }
    S1(0, 0);
    S1(2, 1);
    S3(1, 0, lsb_);
    S3(3, 1, lsb_);
    __syncthreads();
    // p1: store B early, compute S2(A), poll B late (both pairs)
    S4(1, 0, j, lsb_, y1s, yp1s);
    S4(3, 1, j, lsb_, y3s, yp3s);
    S2(0);
    S2(1);
    S5_2(1, 3, j);
    __syncthreads();
    // p2: S3(A) || S1(B, j+1), both pairs
    S3(0, 0, lsb_);
    S3(2, 1, lsb_);
    if (j < 2 * NSTEPS - 1) {
      if (sub_) { STAGE(1, (j + 1) >> 1); STAGE(3, (j + 1) >> 1); }
      S1(1, 0);
      S1(3, 1);
    }
    __syncthreads();
    // p3: store A early, compute S2(B, j+1), poll A late (both pairs)
    S4(0, 0, j, lsb_, y0s, yp0s);
    S4(2, 1, j, lsb_, y2s, yp2s);
    if (j < 2 * NSTEPS - 1) { S2(0); S2(1); }
    S5_2(0, 2, j);
    __syncthreads();
  }

  // ---- logits + softmax (slice-0 WG of each group; 64 rows); LG aliases part
  float* LG = (float*)part;
  if (t == 0) {
    for (int e = tid; e < 64 * 10; e += NTH) {
      int rr = e / 10, cc = e - rr * 10;
      float a = b2[cc];
#pragma unroll 4
      for (int h = 0; h < H; ++h) a += b2f(YB[rr >> 4][rr & 15][h]) * W2[cc * H + h];
      LG[rr * 10 + cc] = a;
    }
    __syncthreads();
    if (tid < 64) {
      float mx = -1e30f;
#pragma unroll
      for (int cc = 0; cc < 10; ++cc) mx = fmaxf(mx, LG[tid * 10 + cc]);
      float ex[10]; float s = 0.f;
#pragma unroll
      for (int cc = 0; cc < 10; ++cc) { ex[cc] = expf(LG[tid * 10 + cc] - mx); s += ex[cc]; }
      float inv = 1.f / s;
#pragma unroll
      for (int cc = 0; cc < 10; ++cc) out[(b0 + tid) * 10 + cc] = ex[cc] * inv;
    }
  }
}

extern "C" void kernel_launch(void* const* d_in, const int* in_sizes, int n_in,
                              void* d_out, int out_size, void* d_ws, size_t ws_size,
                              hipStream_t stream) {
  (void)in_sizes; (void)n_in; (void)out_size; (void)ws_size;
  const float* logsig = (const float*)d_in[1];
  const float* x0     = (const float*)d_in[2];
  const float* Wvf1   = (const float*)d_in[3];
  const float* bvf1   = (const float*)d_in[4];
  const float* Wvf2   = (const float*)d_in[5];
  const float* bvf2   = (const float*)d_in[6];
  const float* Wm     = (const float*)d_in[7];
  const float* bmv    = (const float*)d_in[8];
  const float* W1     = (const float*)d_in[9];
  const float* b1     = (const float*)d_in[10];
  const float* W2     = (const float*)d_in[11];
  const float* b2     = (const float*)d_in[12];
  char* ws = (char*)d_ws;

  prep_scales<<<128, PREPTH, 0, stream>>>(Wm, ws);
  prep_pack<<<3083, PREPTH, 0, stream>>>(Wvf1, Wvf2, Wm, bmv, ws);
  hipMemsetAsync(ws + OFF_YBUF, 0, YBUF_BYTES, stream);  // kill stale tags each call
  rde_main<<<NWG, NTH, 0, stream>>>(logsig, x0, W1, b1, bvf1, bvf2, W2, b2, ws,
                                    (float*)d_out);
}

// Round 16
// 579.937 us; speedup vs baseline: 1.6081x; 1.6081x over previous
//
#include <hip/hip_runtime.h>
#include <hip/hip_bf16.h>

typedef float f32x4 __attribute__((ext_vector_type(4)));
typedef int   i32x4 __attribute__((ext_vector_type(4)));
typedef short s16x8 __attribute__((ext_vector_type(8)));
typedef unsigned short u16;

#define NGP 32       // group-pairs; each = 2 tiles x 16 rows
#define BT 16        // rows per tile
#define NWG 256      // 32 pairs x 8 h-slices
#define NTH 512      // 8 waves
#define PREPTH 256
#define H 128
#define VW 256
#define NI 64
#define NSTEPS 64

// ws BYTE layout:
#define OFF_FRAG16 0        // u16 frags: W1 (32768 u16) + W2 (65536 u16) = 196608 B
#define OFF_WMQ    196608   // i8 frags [slice8][l21][kk4][lane64][16] = 688128 B
#define OFF_BMF    884736   // f32 [slice8][l21][hh16] = 10752 B
#define OFF_SCF    895488   // f32[128]
#define OFF_SINV   896000   // f32[128]
#define OFF_YBUF   896512   // u32 [64 tile][2 parity][2048] = 1 MB
#define YBUF_BYTES 1048576

#define MFMA_BF16(a,b,c) __builtin_amdgcn_mfma_f32_16x16x32_bf16(a,b,c,0,0,0)
#define MFMA_I8(a,b,c)   __builtin_amdgcn_mfma_i32_16x16x64_i8(a,b,c,0,0,0)

__device__ __forceinline__ u16 bf16u(float f) {
  union { float f; unsigned u; } x; x.f = f;
  return (u16)((x.u + 0x7fffu + ((x.u >> 16) & 1u)) >> 16);  // RNE
}
__device__ __forceinline__ float b2f(u16 u) {
  union { unsigned u; float f; } x; x.u = ((unsigned)u) << 16;
  return x.f;
}

// -------- prep 1: per-h max of |Wm| -> scales --------
__global__ void prep_scales(const float* __restrict__ Wm, char* __restrict__ ws) {
  __shared__ float red[4];
  const int tid = threadIdx.x;
  const int h = blockIdx.x;
  float m = 0.f;
  for (int i = tid; i < 21 * VW; i += PREPTH) m = fmaxf(m, fabsf(Wm[h * 21 * VW + i]));
  for (int off = 32; off > 0; off >>= 1) m = fmaxf(m, __shfl_down(m, off));
  if ((tid & 63) == 0) red[tid >> 6] = m;
  __syncthreads();
  if (tid == 0) {
    m = fmaxf(fmaxf(red[0], red[1]), fmaxf(red[2], red[3]));
    m = fmaxf(m, 1e-20f);
    ((float*)(ws + OFF_SCF))[h]  = m / 16129.f;   // max/(127*127)
    ((float*)(ws + OFF_SINV))[h] = 127.f / m;
  }
}

// -------- prep 2: pack W1/W2 bf16 frags, Wm i8 frags, bm slices --------
__global__ void prep_pack(const float* __restrict__ Wvf1, const float* __restrict__ Wvf2,
                          const float* __restrict__ Wm, const float* __restrict__ bmv,
                          char* __restrict__ ws) {
  int idx = blockIdx.x * blockDim.x + threadIdx.x;
  if (idx < 98304) {
    u16* w16 = (u16*)(ws + OFF_FRAG16);
    float val;
    if (idx < 32768) {
      int e = idx;
      int j = e & 7, ln = (e >> 3) & 63, nt = (e >> 9) & 15, kk = e >> 13;
      val = Wvf1[(nt * 16 + (ln & 15)) * H + kk * 32 + (ln >> 4) * 8 + j];
    } else {
      int e = idx - 32768;
      int j = e & 7, ln = (e >> 3) & 63, nt = (e >> 9) & 15, kk = e >> 13;
      val = Wvf2[(nt * 16 + (ln & 15)) * VW + kk * 32 + (ln >> 4) * 8 + j];
    }
    w16[idx] = bf16u(val);
  } else if (idx < 98304 + 688128) {
    int b = idx - 98304;
    int j = b & 15, lane = (b >> 4) & 63, kk = (b >> 10) & 3, rem = b >> 12;
    int l = rem % 21, nt = rem / 21;
    int h = nt * 16 + (lane & 15);
    int w = kk * 64 + (lane >> 4) * 16 + j;
    float sinv = ((const float*)(ws + OFF_SINV))[h];
    float val = Wm[(size_t)(h * 21 + l) * VW + w];
    int q = (int)lrintf(val * sinv);
    q = min(127, max(-127, q));
    ((signed char*)(ws + OFF_WMQ))[b] = (signed char)q;
  } else if (idx < 98304 + 688128 + 2688) {
    int b = idx - (98304 + 688128);
    int hh = b & 15, rem = b >> 4;
    int l = rem % 21, nt = rem / 21;
    ((float*)(ws + OFF_BMF))[b] = bmv[(nt * 16 + hh) * 21 + l];
  }
}

// -------- main persistent kernel: 4-phase dual-tile pipeline --------
__global__ __launch_bounds__(NTH, 1) void rde_main(
    const float* __restrict__ logsig, const float* __restrict__ x0,
    const float* __restrict__ W1, const float* __restrict__ b1,
    const float* __restrict__ bvf1, const float* __restrict__ bvf2,
    const float* __restrict__ W2, const float* __restrict__ b2,
    char* __restrict__ ws, float* __restrict__ out) {
  __shared__ __align__(16) signed char WmL[86016];    // i8 Wm slice (shared)
  __shared__ __align__(16) u16   YB [2][BT][H + 8];   // per-tile bf16 y
  __shared__ __align__(16) u16   V1R[BT][VW + 8];     // time-shared between tiles
  __shared__ __align__(16) signed char V2QH[4096];    // time-shared
  __shared__ __align__(16) float LSF[2][2][21][BT];   // [tile][parity][l][r]
  __shared__ __align__(16) float part[8][BT][17];     // time-shared
  __shared__ __align__(16) float bmL[336];
  __shared__ float scL[16];
  __shared__ float LG[32][10];

  const int tid = threadIdx.x;
  const int lane = tid & 63;
  const int wv = tid >> 6;     // 0..7
  const int c = lane & 15;
  const int kg = lane >> 4;
  const int bid = blockIdx.x;
  const int Gp = (bid & 7) * 4 + (bid >> 6);  // 0..31; pair members share bid%8 (XCD heuristic)
  const int t = (bid >> 3) & 7;               // h-slice 0..7
  const int b0 = Gp * 32;
  unsigned* __restrict__ ybuf = (unsigned*)(ws + OFF_YBUF);
  const s16x8* __restrict__ fr16 = (const s16x8*)(ws + OFF_FRAG16);
  const f32x4 zf = {0.f, 0.f, 0.f, 0.f};
  const i32x4 zi = {0, 0, 0, 0};

  // persistent register weights: wave handles n-tiles {2wv, 2wv+1}
  s16x8 w1r[2][4], w2r[2][8];
#pragma unroll
  for (int n = 0; n < 2; ++n) {
#pragma unroll
    for (int kk = 0; kk < 4; ++kk) w1r[n][kk] = fr16[(kk * 16 + wv * 2 + n) * 64 + lane];
#pragma unroll
    for (int kk = 0; kk < 8; ++kk) w2r[n][kk] = fr16[4096 + (kk * 16 + wv * 2 + n) * 64 + lane];
  }
  float bv1[2], bv2[2];
#pragma unroll
  for (int n = 0; n < 2; ++n) {
    bv1[n] = bvf1[wv * 32 + n * 16 + c];
    bv2[n] = bvf2[wv * 32 + n * 16 + c];
  }

  {  // Wm slice -> LDS (once)
    const i32x4* wsrc = (const i32x4*)(ws + OFF_WMQ + t * 86016);
    i32x4* wdst = (i32x4*)WmL;
    for (int e = tid; e < 5376; e += NTH) wdst[e] = wsrc[e];
  }
  if (tid < 16) scL[tid] = ((const float*)(ws + OFF_SCF))[t * 16 + tid];
  for (int e = tid; e < 336; e += NTH) bmL[e] = ((const float*)(ws + OFF_BMF))[t * 336 + e];

  // y0 = x0 @ W1^T + b1 for both tiles (full YB + own state elements)
  for (int e = tid; e < 2 * BT * H; e += NTH) {
    int tt = e >> 11, r = (e >> 7) & 15, h = e & 127;
    float a = b1[h];
#pragma unroll
    for (int d = 0; d < 6; ++d) a += x0[(b0 + tt * 16 + r) * 6 + d] * W1[h * 6 + d];
    YB[tt][r][h] = bf16u(a);
  }
  float y0s = 0.f, y1s = 0.f, yp0s = 0.f, yp1s = 0.f;
  if (tid < 256) {
    int r = tid >> 4, hh = tid & 15, h = t * 16 + hh;
    float a0 = b1[h], a1 = b1[h];
#pragma unroll
    for (int d = 0; d < 6; ++d) {
      a0 += x0[(b0 + r) * 6 + d] * W1[h * 6 + d];
      a1 += x0[(b0 + 16 + r) * 6 + d] * W1[h * 6 + d];
    }
    y0s = a0; y1s = a1;
  }

  // ---- pipeline stage helpers ----
  auto STAGE = [&](int T, int iv) {
    if (tid < BT * 21) {
      int r = tid / 21, l = tid - r * 21;
      LSF[T][iv & 1][l][r] = logsig[((size_t)(b0 + T * 16 + r) * NI + iv) * 22 + 1 + l];
    }
  };
  auto S1 = [&](int T) {  // YB[T] -> V1R (relu(y @ W1^T + b1))
    s16x8 ay0 = *(const s16x8*)&YB[T][c][0 * 32 + kg * 8];
    s16x8 ay1 = *(const s16x8*)&YB[T][c][1 * 32 + kg * 8];
    s16x8 ay2 = *(const s16x8*)&YB[T][c][2 * 32 + kg * 8];
    s16x8 ay3 = *(const s16x8*)&YB[T][c][3 * 32 + kg * 8];
    f32x4 pA = MFMA_BF16(ay0, w1r[0][0], zf), pB = MFMA_BF16(ay0, w1r[1][0], zf);
    pA = MFMA_BF16(ay1, w1r[0][1], pA);  pB = MFMA_BF16(ay1, w1r[1][1], pB);
    pA = MFMA_BF16(ay2, w1r[0][2], pA);  pB = MFMA_BF16(ay2, w1r[1][2], pB);
    pA = MFMA_BF16(ay3, w1r[0][3], pA);  pB = MFMA_BF16(ay3, w1r[1][3], pB);
#pragma unroll
    for (int q = 0; q < 4; ++q) {
      V1R[kg * 4 + q][wv * 32 + c]      = bf16u(fmaxf(pA[q] + bv1[0], 0.f));
      V1R[kg * 4 + q][wv * 32 + 16 + c] = bf16u(fmaxf(pB[q] + bv1[1], 0.f));
    }
  };
  auto S2 = [&]() {  // V1R -> V2QH (tanh + i8 quantize, hi only)
    s16x8 av0 = *(const s16x8*)&V1R[c][0 * 32 + kg * 8];
    s16x8 av1 = *(const s16x8*)&V1R[c][1 * 32 + kg * 8];
    s16x8 av2 = *(const s16x8*)&V1R[c][2 * 32 + kg * 8];
    s16x8 av3 = *(const s16x8*)&V1R[c][3 * 32 + kg * 8];
    s16x8 av4 = *(const s16x8*)&V1R[c][4 * 32 + kg * 8];
    s16x8 av5 = *(const s16x8*)&V1R[c][5 * 32 + kg * 8];
    s16x8 av6 = *(const s16x8*)&V1R[c][6 * 32 + kg * 8];
    s16x8 av7 = *(const s16x8*)&V1R[c][7 * 32 + kg * 8];
    f32x4 pA = MFMA_BF16(av0, w2r[0][0], zf), pB = MFMA_BF16(av0, w2r[1][0], zf);
    pA = MFMA_BF16(av1, w2r[0][1], pA);  pB = MFMA_BF16(av1, w2r[1][1], pB);
    pA = MFMA_BF16(av2, w2r[0][2], pA);  pB = MFMA_BF16(av2, w2r[1][2], pB);
    pA = MFMA_BF16(av3, w2r[0][3], pA);  pB = MFMA_BF16(av3, w2r[1][3], pB);
    pA = MFMA_BF16(av4, w2r[0][4], pA);  pB = MFMA_BF16(av4, w2r[1][4], pB);
    pA = MFMA_BF16(av5, w2r[0][5], pA);  pB = MFMA_BF16(av5, w2r[1][5], pB);
    pA = MFMA_BF16(av6, w2r[0][6], pA);  pB = MFMA_BF16(av6, w2r[1][6], pB);
    pA = MFMA_BF16(av7, w2r[0][7], pA);  pB = MFMA_BF16(av7, w2r[1][7], pB);
#pragma unroll
    for (int n = 0; n < 2; ++n) {
      f32x4 p = n ? pB : pA;
#pragma unroll
      for (int q = 0; q < 4; ++q) {
        float x = p[q] + bv2[n];
        float e2 = __expf(2.f * x);
        float t127 = fmaf(-254.f, __builtin_amdgcn_rcpf(e2 + 1.f), 127.f);  // 127*tanh
        int bo = ((wv >> 1) * 64 + ((wv & 1) * 2 + n) * 16 + kg * 4 + q) * 16 + c;
        V2QH[bo] = (signed char)(int)rintf(t127);
      }
    }
  };
  auto S3 = [&](int T, int lsb_) {  // V2QH x WmL -> part (ls-folded)
    i32x4 aih0 = *(const i32x4*)&V2QH[(0 * 64 + lane) * 16];
    i32x4 aih1 = *(const i32x4*)&V2QH[(1 * 64 + lane) * 16];
    i32x4 aih2 = *(const i32x4*)&V2QH[(2 * 64 + lane) * 16];
    i32x4 aih3 = *(const i32x4*)&V2QH[(3 * 64 + lane) * 16];
    const int nl = (wv < 5) ? 3 : 2;
    const int lb = (wv < 5) ? 3 * wv : 15 + 2 * (wv - 5);
    f32x4 acc = zf;
    for (int li = 0; li < nl; ++li) {
      int l = lb + li;
      const i32x4* bp = (const i32x4*)WmL + l * 256 + lane;
      i32x4 bq0 = bp[0], bq1 = bp[64], bq2 = bp[128], bq3 = bp[192];
      i32x4 PH = MFMA_I8(aih0, bq0, zi);
      PH = MFMA_I8(aih1, bq1, PH);
      PH = MFMA_I8(aih2, bq2, PH);
      PH = MFMA_I8(aih3, bq3, PH);
      f32x4 ls4 = *(const f32x4*)&LSF[T][lsb_][l][kg * 4];
#pragma unroll
      for (int q = 0; q < 4; ++q) acc[q] += ls4[q] * (float)PH[q];
    }
#pragma unroll
    for (int q = 0; q < 4; ++q) part[wv][kg * 4 + q][c] = acc[q];
  };
  auto S4 = [&](int T, int j, int lsb_, float& y, float& yp) {  // Heun + tagged store
    if (tid < 256) {
      int r = tid >> 4, hh = tid & 15;
      float s = ((part[0][r][hh] + part[1][r][hh]) + (part[2][r][hh] + part[3][r][hh])) +
                ((part[4][r][hh] + part[5][r][hh]) + (part[6][r][hh] + part[7][r][hh]));
      float bmd = 0.f;
#pragma unroll
      for (int l = 0; l < 21; ++l) bmd += LSF[T][lsb_][l][r] * bmL[l * 16 + hh];
      float raw = scL[hh] * s + bmd;
      float yn;
      if (!(j & 1)) { yp = y + 0.5f * raw; yn = y + raw; }
      else          { y = yp + 0.5f * raw; yn = y; }
      unsigned v = ((unsigned)(j + 1) << 16) | (unsigned)bf16u(yn);
      __hip_atomic_store(&ybuf[((Gp * 2 + T) * 2 + (j & 1)) * 2048 + r * 128 + t * 16 + hh],
                         v, __ATOMIC_RELAXED, __HIP_MEMORY_SCOPE_AGENT);
    }
  };
  auto S5 = [&](int T, int j) {  // poll peers' tags, rebuild YB[T]
    const unsigned tg = (unsigned)(j + 1);
    const unsigned* pb = ybuf + ((Gp * 2 + T) * 2 + (j & 1)) * 2048;
    unsigned v0, v1, v2, v3;
#pragma unroll 1
    for (int sp = 0; sp < 60000; ++sp) {
      v0 = __hip_atomic_load(&pb[tid],        __ATOMIC_RELAXED, __HIP_MEMORY_SCOPE_AGENT);
      v1 = __hip_atomic_load(&pb[tid + 512],  __ATOMIC_RELAXED, __HIP_MEMORY_SCOPE_AGENT);
      v2 = __hip_atomic_load(&pb[tid + 1024], __ATOMIC_RELAXED, __HIP_MEMORY_SCOPE_AGENT);
      v3 = __hip_atomic_load(&pb[tid + 1536], __ATOMIC_RELAXED, __HIP_MEMORY_SCOPE_AGENT);
      unsigned mn = min(min(v0 >> 16, v1 >> 16), min(v2 >> 16, v3 >> 16));
      if (mn == tg) break;
    }
    YB[T][tid >> 7][tid & 127] = (u16)(v0 & 0xffffu);
    YB[T][(tid + 512) >> 7][(tid + 512) & 127] = (u16)(v1 & 0xffffu);
    YB[T][(tid + 1024) >> 7][(tid + 1024) & 127] = (u16)(v2 & 0xffffu);
    YB[T][(tid + 1536) >> 7][(tid + 1536) & 127] = (u16)(v3 & 0xffffu);
  };

  __syncthreads();

  // ---- pipeline prologue: tile B runs S1,S2 of sub-step 0
  STAGE(1, 0);
  __syncthreads();
  S1(1);
  __syncthreads();
  S2();
  __syncthreads();

#pragma unroll 1
  for (int j = 0; j < 2 * NSTEPS; ++j) {
    const int step_ = j >> 1, sub_ = j & 1;
    const int lsb_ = (sub_ ? step_ : (step_ > 0 ? step_ - 1 : 0)) & 1;
    // p0: S1(A,j) || S3(B,j)
    if (!sub_) STAGE(0, step_);
    S1(0);
    S3(1, lsb_);
    __syncthreads();
    // p1: store B early, compute S2(A), poll B late
    S4(1, j, lsb_, y1s, yp1s);
    S2();
    S5(1, j);
    __syncthreads();
    // p2: S3(A,j) || S1(B,j+1)
    S3(0, lsb_);
    if (j < 2 * NSTEPS - 1) {
      if (sub_) STAGE(1, (j + 1) >> 1);
      S1(1);
    }
    __syncthreads();
    // p3: store A early, compute S2(B,j+1), poll A late
    S4(0, j, lsb_, y0s, yp0s);
    if (j < 2 * NSTEPS - 1) S2();
    S5(0, j);
    __syncthreads();
  }

  // ---- logits + softmax (slice-0 WG of each pair; 32 rows)
  if (t == 0) {
    for (int e = tid; e < 32 * 10; e += NTH) {
      int rr = e / 10, cc = e - rr * 10;
      float a = b2[cc];
#pragma unroll 4
      for (int h = 0; h < H; ++h) a += b2f(YB[rr >> 4][rr & 15][h]) * W2[cc * H + h];
      LG[rr][cc] = a;
    }
    __syncthreads();
    if (tid < 32) {
      float mx = -1e30f;
#pragma unroll
      for (int cc = 0; cc < 10; ++cc) mx = fmaxf(mx, LG[tid][cc]);
      float ex[10]; float s = 0.f;
#pragma unroll
      for (int cc = 0; cc < 10; ++cc) { ex[cc] = expf(LG[tid][cc] - mx); s += ex[cc]; }
      float inv = 1.f / s;
#pragma unroll
      for (int cc = 0; cc < 10; ++cc) out[(b0 + tid) * 10 + cc] = ex[cc] * inv;
    }
  }
}

extern "C" void kernel_launch(void* const* d_in, const int* in_sizes, int n_in,
                              void* d_out, int out_size, void* d_ws, size_t ws_size,
                              hipStream_t stream) {
  (void)in_sizes; (void)n_in; (void)out_size; (void)ws_size;
  const float* logsig = (const float*)d_in[1];
  const float* x0     = (const float*)d_in[2];
  const float* Wvf1   = (const float*)d_in[3];
  const float* bvf1   = (const float*)d_in[4];
  const float* Wvf2   = (const float*)d_in[5];
  const float* bvf2   = (const float*)d_in[6];
  const float* Wm     = (const float*)d_in[7];
  const float* bmv    = (const float*)d_in[8];
  const float* W1     = (const float*)d_in[9];
  const float* b1     = (const float*)d_in[10];
  const float* W2     = (const float*)d_in[11];
  const float* b2     = (const float*)d_in[12];
  char* ws = (char*)d_ws;

  prep_scales<<<128, PREPTH, 0, stream>>>(Wm, ws);
  prep_pack<<<3083, PREPTH, 0, stream>>>(Wvf1, Wvf2, Wm, bmv, ws);
  hipMemsetAsync(ws + OFF_YBUF, 0, YBUF_BYTES, stream);  // kill stale tags each call
  rde_main<<<NWG, NTH, 0, stream>>>(logsig, x0, W1, b1, bvf1, bvf2, W2, b2, ws,
                                    (float*)d_out);
}